// Round 2
// baseline (902.206 us; speedup 1.0000x reference)
//
#include <hip/hip_runtime.h>
#include <math.h>

#define B_ROWS 4096
#define P_ROWS 4096
#define KD     512
#define TOPK   4
#define L_LEN  16
#define E_DIM  512

// ---------------- Kernel 1: row inverse L2 norms (x rows then key rows) ----
__global__ __launch_bounds__(64) void norms_kernel(const float* __restrict__ x,
                                                   const float* __restrict__ keys,
                                                   float* __restrict__ invx,
                                                   float* __restrict__ invk) {
    int row = blockIdx.x;                       // 0..8191
    const float* src = (row < B_ROWS) ? (x + (size_t)row * KD)
                                      : (keys + (size_t)(row - B_ROWS) * KD);
    int lane = threadIdx.x;                     // 64 threads = 1 wave
    const float4* s4 = (const float4*)src;      // 128 float4 per row
    float sum = 0.f;
#pragma unroll
    for (int i = 0; i < 2; ++i) {
        float4 v = s4[lane + i * 64];
        sum += v.x * v.x + v.y * v.y + v.z * v.z + v.w * v.w;
    }
#pragma unroll
    for (int off = 32; off > 0; off >>= 1) sum += __shfl_down(sum, off);
    if (lane == 0) {
        float inv = 1.0f / sqrtf(fmaxf(sum, 1e-12f));
        if (row < B_ROWS) invx[row] = inv; else invk[row - B_ROWS] = inv;
    }
}

// ---------------- Kernel 2: scores = -(x . k^T) * invx * invk --------------
// 64x64 tile per 256-thread block, BK=16, each thread computes 4x4.
__global__ __launch_bounds__(256) void scores_kernel(const float* __restrict__ X,
                                                     const float* __restrict__ KY,
                                                     const float* __restrict__ invx,
                                                     const float* __restrict__ invk,
                                                     float* __restrict__ S) {
    __shared__ float As[16][64];   // [k][m]
    __shared__ float Bs[16][64];   // [k][n]
    const int tid = threadIdx.x;
    const int tx = tid & 15;       // col group 0..15
    const int ty = tid >> 4;       // row group 0..15
    const int bm = blockIdx.y * 64;
    const int bn = blockIdx.x * 64;

    const int lr = tid >> 2;         // load row 0..63
    const int lc = (tid & 3) << 2;   // load col {0,4,8,12}

    float acc[4][4] = {};

    for (int k0 = 0; k0 < KD; k0 += 16) {
        float4 a = *(const float4*)(X  + (size_t)(bm + lr) * KD + k0 + lc);
        float4 b = *(const float4*)(KY + (size_t)(bn + lr) * KD + k0 + lc);
        __syncthreads();   // previous iteration's reads done before overwrite
        As[lc + 0][lr] = a.x; As[lc + 1][lr] = a.y;
        As[lc + 2][lr] = a.z; As[lc + 3][lr] = a.w;
        Bs[lc + 0][lr] = b.x; Bs[lc + 1][lr] = b.y;
        Bs[lc + 2][lr] = b.z; Bs[lc + 3][lr] = b.w;
        __syncthreads();
#pragma unroll
        for (int kk = 0; kk < 16; ++kk) {
            const float4 av = *(const float4*)(&As[kk][ty * 4]);
            const float4 bv = *(const float4*)(&Bs[kk][tx * 4]);
            const float am[4] = {av.x, av.y, av.z, av.w};
            const float bm_[4] = {bv.x, bv.y, bv.z, bv.w};
#pragma unroll
            for (int i = 0; i < 4; ++i)
#pragma unroll
                for (int j = 0; j < 4; ++j)
                    acc[i][j] = fmaf(am[i], bm_[j], acc[i][j]);
        }
    }

    float ix[4], ik[4];
#pragma unroll
    for (int i = 0; i < 4; ++i) ix[i] = invx[bm + ty * 4 + i];
#pragma unroll
    for (int j = 0; j < 4; ++j) ik[j] = invk[bn + tx * 4 + j];
#pragma unroll
    for (int i = 0; i < 4; ++i) {
        float4 o;
        o.x = -acc[i][0] * ix[i] * ik[0];
        o.y = -acc[i][1] * ix[i] * ik[1];
        o.z = -acc[i][2] * ix[i] * ik[2];
        o.w = -acc[i][3] * ix[i] * ik[3];
        *(float4*)(S + (size_t)(bm + ty * 4 + i) * P_ROWS + bn + tx * 4) = o;
    }
}

// ---------------- Kernel 3: top-4 per row, jax.lax.top_k semantics ---------
// comparator: (v1 > v2) || (v1 == v2 && i1 < i2)  => 1 ranks before 2
__device__ __forceinline__ bool better(float v1, int i1, float v2, int i2) {
    return (v1 > v2) || (v1 == v2 && i1 < i2);
}

__global__ __launch_bounds__(256) void topk_kernel(const float* __restrict__ S,
                                                   int* __restrict__ outidx) {
    __shared__ float sv[256][4];
    __shared__ int   si[256][4];
    const int b = blockIdx.x;
    const float* row = S + (size_t)b * P_ROWS;

    float v[4]  = {-3.402823466e38f, -3.402823466e38f, -3.402823466e38f, -3.402823466e38f};
    int   id[4] = {0x7fffffff, 0x7fffffff, 0x7fffffff, 0x7fffffff};

    for (int p = threadIdx.x; p < P_ROWS; p += 256) {
        float s = row[p];
        if (better(s, p, v[3], id[3])) {
            v[3] = s; id[3] = p;
#pragma unroll
            for (int j = 3; j > 0; --j) {
                if (better(v[j], id[j], v[j - 1], id[j - 1])) {
                    float tv = v[j]; v[j] = v[j - 1]; v[j - 1] = tv;
                    int   ti = id[j]; id[j] = id[j - 1]; id[j - 1] = ti;
                }
            }
        }
    }
#pragma unroll
    for (int j = 0; j < 4; ++j) { sv[threadIdx.x][j] = v[j]; si[threadIdx.x][j] = id[j]; }
    __syncthreads();

    for (int s = 128; s >= 1; s >>= 1) {
        if (threadIdx.x < (unsigned)s) {
            float av[4], bv[4]; int ai[4], bi[4];
#pragma unroll
            for (int j = 0; j < 4; ++j) {
                av[j] = sv[threadIdx.x][j];     ai[j] = si[threadIdx.x][j];
                bv[j] = sv[threadIdx.x + s][j]; bi[j] = si[threadIdx.x + s][j];
            }
            float rv[4]; int ri[4];
            int xx = 0, yy = 0;
#pragma unroll
            for (int o = 0; o < 4; ++o) {
                bool takeA;
                if (xx >= 4) takeA = false;
                else if (yy >= 4) takeA = true;
                else takeA = better(av[xx], ai[xx], bv[yy], bi[yy]);
                if (takeA) { rv[o] = av[xx]; ri[o] = ai[xx]; ++xx; }
                else       { rv[o] = bv[yy]; ri[o] = bi[yy]; ++yy; }
            }
#pragma unroll
            for (int j = 0; j < 4; ++j) { sv[threadIdx.x][j] = rv[j]; si[threadIdx.x][j] = ri[j]; }
        }
        __syncthreads();
    }
    if (threadIdx.x == 0) {
#pragma unroll
        for (int j = 0; j < 4; ++j) outidx[b * 4 + j] = si[0][j];
    }
}

// ---------------- Kernel 4: gather prompt_values rows ----------------------
// one wave per output row (b, j): 512 floats = 128 float4, 64 lanes x 2
__global__ __launch_bounds__(256) void gather_kernel(const float* __restrict__ pv,
                                                     const int* __restrict__ topidx,
                                                     float* __restrict__ out) {
    int gw   = (blockIdx.x << 2) | (threadIdx.x >> 6);  // global wave id
    int lane = threadIdx.x & 63;
    int b = gw >> 6;
    int j = gw & 63;          // 0..63 = ki*16 + l
    int ki = j >> 4, l = j & 15;
    int p = topidx[(b << 2) | ki];
    const float4* src = (const float4*)(pv + ((size_t)p * L_LEN + l) * E_DIM);
    float4*       dst = (float4*)(out + ((size_t)b * 64 + j) * E_DIM);
    dst[lane]      = src[lane];
    dst[lane + 64] = src[lane + 64];
}

extern "C" void kernel_launch(void* const* d_in, const int* in_sizes, int n_in,
                              void* d_out, int out_size, void* d_ws, size_t ws_size,
                              hipStream_t stream) {
    (void)in_sizes; (void)n_in; (void)out_size; (void)ws_size;
    const float* x    = (const float*)d_in[0];   // (4096,64,8) -> (4096,512)
    const float* keys = (const float*)d_in[1];   // (4096,512)
    const float* pv   = (const float*)d_in[2];   // (4096,16,512)
    float* out = (float*)d_out;                  // (4096,64,512)

    float* invx   = (float*)d_ws;                // 4096 f
    float* invk   = invx + B_ROWS;               // 4096 f
    int*   topidx = (int*)(invk + P_ROWS);       // 4096*4 i32
    float* scores = out;                         // reuse d_out head (64 MB of 512 MB)

    norms_kernel<<<B_ROWS + P_ROWS, 64, 0, stream>>>(x, keys, invx, invk);

    dim3 g2(P_ROWS / 64, B_ROWS / 64);
    scores_kernel<<<g2, 256, 0, stream>>>(x, keys, invx, invk, scores);

    topk_kernel<<<B_ROWS, 256, 0, stream>>>(scores, topidx);

    gather_kernel<<<(B_ROWS * 64) / 4, 256, 0, stream>>>(pv, topidx, out);
}